// Round 1
// baseline (7138.509 us; speedup 1.0000x reference)
//
#include <hip/hip_runtime.h>
#include <hip/hip_bf16.h>

// Problem constants
#define SEQ   2048
#define HID   1024
#define INP   576
#define G4H   4096   // 4*HID
#define NOUT  32001

typedef __attribute__((ext_vector_type(8))) short bf16x8;
typedef __attribute__((ext_vector_type(4))) float f32x4;

__device__ __forceinline__ unsigned short f2bf(float f) {
  unsigned int u = __builtin_bit_cast(unsigned int, f);
  unsigned int r = (u + 0x7FFFu + ((u >> 16) & 1u)) >> 16;
  return (unsigned short)r;
}
__device__ __forceinline__ float bf2f(unsigned short h) {
  unsigned int u = ((unsigned int)h) << 16;
  return __builtin_bit_cast(float, u);
}

// ---------------------------------------------------------------- embedding
__global__ __launch_bounds__(128)
void k_embed(const int* __restrict__ loc, const int* __restrict__ tim,
             const float* __restrict__ el, const float* __restrict__ et,
             unsigned short* __restrict__ xbf) {
  int s = blockIdx.x;
  int l = loc[s], t = tim[s];
  for (int c = threadIdx.x; c < INP; c += 128) {
    float v = (c < 512) ? el[(size_t)l * 512 + c] : et[(size_t)t * 64 + (c - 512)];
    xbf[(size_t)s * INP + c] = f2bf(v);
  }
}

// ---------------------------------------------------------------- GEMM (B^T layout)
// C[m][n] = sum_k A[m][k] * Bt[n][k] (+ bias0[n] + bias1[n])
// A: bf16 [M][lda]. Bt: bf16 (BSRC=0) or fp32 (BSRC=1, converted during staging) [N][ldb].
// OUTBF: 0 -> fp32 C, 1 -> bf16 C. TRI: skip blocks fully above diagonal (energies).
// blockIdx.x -> m tile (m-major so same-n blocks run together for B reuse in L2/L3).
template<int BSRC, int OUTBF, int TRI>
__global__ __launch_bounds__(256)
void k_gemm(const unsigned short* __restrict__ A, int lda,
            const void* __restrict__ B, int ldb,
            void* __restrict__ C, long long ldc, long long cofs,
            int M, int N, int K,
            const float* __restrict__ bias0, const float* __restrict__ bias1) {
  int m0 = blockIdx.x * 128;
  int n0 = blockIdx.y * 128;
  if (TRI && n0 > m0 + 127) return;

  __shared__ unsigned short sA[128][40];  // 32 + 8 pad
  __shared__ unsigned short sB[128][40];

  int tid = threadIdx.x;
  int lane = tid & 63;
  int wid = tid >> 6;
  int wm = (wid >> 1) * 64, wn = (wid & 1) * 64;
  int r16 = lane & 15, quad = lane >> 4;

  f32x4 acc[4][4];
#pragma unroll
  for (int i = 0; i < 4; ++i)
#pragma unroll
    for (int j = 0; j < 4; ++j)
#pragma unroll
      for (int r = 0; r < 4; ++r) acc[i][j][r] = 0.f;

  int nk = K / 32;
  for (int kt = 0; kt < nk; ++kt) {
    int k0 = kt * 32;
#pragma unroll
    for (int h = 0; h < 2; ++h) {       // A staging: 512 chunks of 8 bf16
      int c = tid + h * 256;
      int row = c >> 2, part = c & 3;
      bf16x8 av = *(const bf16x8*)(A + (size_t)(m0 + row) * lda + k0 + part * 8);
      *(bf16x8*)&sA[row][part * 8] = av;
    }
#pragma unroll
    for (int h = 0; h < 2; ++h) {       // B staging (optionally fp32->bf16)
      int c = tid + h * 256;
      int row = c >> 2, part = c & 3;
      int gr = n0 + row;
      bf16x8 bv;
      if (gr < N) {
        if (BSRC == 0) {
          bv = *(const bf16x8*)((const unsigned short*)B + (size_t)gr * ldb + k0 + part * 8);
        } else {
          const float* bp = (const float*)B + (size_t)gr * ldb + k0 + part * 8;
          f32x4 b0 = *(const f32x4*)bp;
          f32x4 b1 = *(const f32x4*)(bp + 4);
#pragma unroll
          for (int z = 0; z < 4; ++z) bv[z] = (short)f2bf(b0[z]);
#pragma unroll
          for (int z = 0; z < 4; ++z) bv[4 + z] = (short)f2bf(b1[z]);
        }
      } else {
#pragma unroll
        for (int z = 0; z < 8; ++z) bv[z] = 0;
      }
      *(bf16x8*)&sB[row][part * 8] = bv;
    }
    __syncthreads();
    bf16x8 af[4], bfr[4];
#pragma unroll
    for (int i = 0; i < 4; ++i) {
      af[i]  = *(const bf16x8*)&sA[wm + i * 16 + r16][quad * 8];
      bfr[i] = *(const bf16x8*)&sB[wn + i * 16 + r16][quad * 8];
    }
#pragma unroll
    for (int i = 0; i < 4; ++i)
#pragma unroll
      for (int j = 0; j < 4; ++j)
        acc[i][j] = __builtin_amdgcn_mfma_f32_16x16x32_bf16(af[i], bfr[j], acc[i][j], 0, 0, 0);
    __syncthreads();
  }

  // epilogue: row = quad*4 + r, col = lane&15 within each 16x16 tile
#pragma unroll
  for (int i = 0; i < 4; ++i) {
    int rowb = m0 + wm + i * 16 + quad * 4;
#pragma unroll
    for (int j = 0; j < 4; ++j) {
      int col = n0 + wn + j * 16 + r16;
      if (col >= N) continue;
      float b = 0.f;
      if (bias0) b += bias0[col];
      if (bias1) b += bias1[col];
#pragma unroll
      for (int r = 0; r < 4; ++r) {
        float v = acc[i][j][r] + b;
        size_t idx = (size_t)(rowb + r) * (size_t)ldc + (size_t)cofs + col;
        if (OUTBF) ((unsigned short*)C)[idx] = f2bf(v);
        else       ((float*)C)[idx] = v;
      }
    }
  }
}

// ---------------------------------------------------------------- persistent LSTM scan
// 256 blocks (1/CU, all co-resident). Block b owns h indices [4b, 4b+4) i.e. 16 gate rows.
// Sync: h published as (tag<<16)|bf16 via agent-scope atomics; consumers poll tags.
__global__ __launch_bounds__(256)
void k_lstm(const float* __restrict__ Whh, const float* __restrict__ xg,
            unsigned int* __restrict__ hglob,
            unsigned short* __restrict__ hs_bf, unsigned short* __restrict__ hsT_bf,
            unsigned short* __restrict__ out_bf) {
  __shared__ unsigned short sW[16][1024];  // 32 KB: this block's W_hh rows, bf16
  __shared__ float sH[1024];
  __shared__ float sZ[16];

  int blk = blockIdx.x;
  int tid = threadIdx.x;
  int r = tid >> 4, kl = tid & 15;       // 16 rows x 16 k-lanes

  {  // load W chunk: local row r -> gate q=r>>2, j=r&3, global row q*1024 + blk*4 + j
    int q = r >> 2, j = r & 3;
    int gr = q * HID + blk * 4 + j;
    const float* wrow = Whh + (size_t)gr * HID;
    for (int c = kl * 64; c < kl * 64 + 64; c += 4) {
      f32x4 w = *(const f32x4*)(wrow + c);
      sW[r][c]     = f2bf(w[0]);
      sW[r][c + 1] = f2bf(w[1]);
      sW[r][c + 2] = f2bf(w[2]);
      sW[r][c + 3] = f2bf(w[3]);
    }
  }
  float cst = 0.f;  // cell state (live in threads tid<4)
  __syncthreads();

  int gr_row = (r >> 2) * HID + blk * 4 + (r & 3);

  for (int t = 0; t < SEQ; ++t) {
    float xgv = 0.f;
    if (kl == 0) xgv = xg[(size_t)t * G4H + gr_row];  // prefetch before polling

    if (t == 0) {
      for (int i = tid; i < HID; i += 256) sH[i] = 0.f;
    } else {
      const unsigned int* src = hglob + (size_t)(t - 1) * HID;
      unsigned int want = (unsigned int)t;
#pragma unroll
      for (int i = 0; i < 4; ++i) {
        int idx = tid * 4 + i;
        unsigned int v;
        do {
          v = __hip_atomic_load(&src[idx], __ATOMIC_RELAXED, __HIP_MEMORY_SCOPE_AGENT);
        } while ((v >> 16) != want);
        sH[idx] = bf2f((unsigned short)(v & 0xFFFFu));
      }
    }
    __syncthreads();

    // z[r] = xg + dot(W[r], h): each thread 64 MACs (8 chunks of 8, stride-16 by kl)
    float acc = 0.f;
#pragma unroll
    for (int kk = 0; kk < 8; ++kk) {
      int k0 = (kk * 16 + kl) * 8;
      bf16x8 wv = *(const bf16x8*)&sW[r][k0];
#pragma unroll
      for (int z = 0; z < 8; ++z)
        acc += bf2f((unsigned short)wv[z]) * sH[k0 + z];
    }
    acc += __shfl_xor(acc, 1);
    acc += __shfl_xor(acc, 2);
    acc += __shfl_xor(acc, 4);
    acc += __shfl_xor(acc, 8);
    if (kl == 0) sZ[r] = acc + xgv;
    __syncthreads();

    if (tid < 4) {
      int j = tid;
      float zi = sZ[j], zf = sZ[4 + j], zg = sZ[8 + j], zo = sZ[12 + j];
      float gi = 1.f / (1.f + __expf(-zi));
      float gf = 1.f / (1.f + __expf(-zf));
      float gg = tanhf(zg);
      float go = 1.f / (1.f + __expf(-zo));
      cst = gf * cst + gi * gg;
      float h = go * tanhf(cst);
      unsigned short hb = f2bf(h);
      int gj = blk * 4 + j;
      __hip_atomic_store(&hglob[(size_t)t * HID + gj],
                         (((unsigned int)(t + 1)) << 16) | (unsigned int)hb,
                         __ATOMIC_RELAXED, __HIP_MEMORY_SCOPE_AGENT);
      hs_bf[(size_t)t * HID + gj] = hb;          // A/B for energies
      hsT_bf[(size_t)gj * SEQ + t] = hb;         // B^T for context GEMM
      out_bf[(size_t)t * (2 * HID) + gj] = hb;   // left half of concat(hs, context)
    }
    // no trailing barrier needed: next iter's sH fill is fenced by the post-fill barrier
  }
}

// ---------------------------------------------------------------- causal softmax rows
__global__ __launch_bounds__(256)
void k_softmax(const float* __restrict__ E, unsigned short* __restrict__ P) {
  int i = blockIdx.x;
  int n = i + 1;
  const float* e = E + (size_t)i * SEQ;
  __shared__ float red[4];
  int tid = threadIdx.x, lane = tid & 63, w = tid >> 6;

  float m = -1e30f;
  for (int j = tid; j < n; j += 256) m = fmaxf(m, e[j]);
  for (int o = 32; o; o >>= 1) m = fmaxf(m, __shfl_xor(m, o));
  if (lane == 0) red[w] = m;
  __syncthreads();
  m = fmaxf(fmaxf(red[0], red[1]), fmaxf(red[2], red[3]));
  __syncthreads();

  float s = 0.f;
  for (int j = tid; j < n; j += 256) s += __expf(e[j] - m);
  for (int o = 32; o; o >>= 1) s += __shfl_xor(s, o);
  if (lane == 0) red[w] = s;
  __syncthreads();
  s = red[0] + red[1] + red[2] + red[3];
  float inv = 1.f / s;

  unsigned short* p = P + (size_t)i * SEQ;
  for (int j = tid; j < SEQ; j += 256)
    p[j] = (j < n) ? f2bf(__expf(e[j] - m) * inv) : (unsigned short)0;
}

// ---------------------------------------------------------------- in-place log-softmax
__global__ __launch_bounds__(256)
void k_logsoftmax(float* __restrict__ Y) {
  int i = blockIdx.x;
  float* y = Y + (size_t)i * (size_t)NOUT;
  __shared__ float red[4];
  int tid = threadIdx.x, lane = tid & 63, w = tid >> 6;

  float m = -1e30f;
  for (int j = tid; j < NOUT; j += 256) m = fmaxf(m, y[j]);
  for (int o = 32; o; o >>= 1) m = fmaxf(m, __shfl_xor(m, o));
  if (lane == 0) red[w] = m;
  __syncthreads();
  m = fmaxf(fmaxf(red[0], red[1]), fmaxf(red[2], red[3]));
  __syncthreads();

  float s = 0.f;
  for (int j = tid; j < NOUT; j += 256) s += __expf(y[j] - m);
  for (int o = 32; o; o >>= 1) s += __shfl_xor(s, o);
  if (lane == 0) red[w] = s;
  __syncthreads();
  s = red[0] + red[1] + red[2] + red[3];
  float lse = m + logf(s);

  for (int j = tid; j < NOUT; j += 256) y[j] -= lse;
}

// ---------------------------------------------------------------- launch
extern "C" void kernel_launch(void* const* d_in, const int* in_sizes, int n_in,
                              void* d_out, int out_size, void* d_ws, size_t ws_size,
                              hipStream_t stream) {
  (void)in_sizes; (void)n_in; (void)out_size; (void)ws_size;
  const int*   loc     = (const int*)d_in[0];
  const int*   tim     = (const int*)d_in[1];
  const float* emb_loc = (const float*)d_in[2];
  const float* emb_tim = (const float*)d_in[3];
  const float* W_ih    = (const float*)d_in[4];
  const float* W_hh    = (const float*)d_in[5];
  const float* b_ih    = (const float*)d_in[6];
  const float* b_hh    = (const float*)d_in[7];
  const float* W_fc    = (const float*)d_in[8];
  const float* b_fc    = (const float*)d_in[9];

  char* ws = (char*)d_ws;
  size_t off = 0;
  auto alloc = [&](size_t bytes) {
    void* p = ws + off;
    off += (bytes + 255) & ~(size_t)255;
    return p;
  };
  unsigned short* xbf    = (unsigned short*)alloc((size_t)SEQ * INP * 2);        // 2.4 MB
  float*          xg     = (float*)         alloc((size_t)SEQ * G4H * 4);        // 33.6 MB
  unsigned int*   hglob  = (unsigned int*)  alloc((size_t)SEQ * HID * 4);        // 8.4 MB
  unsigned short* hs_bf  = (unsigned short*)alloc((size_t)SEQ * HID * 2);        // 4.2 MB
  unsigned short* hsT_bf = (unsigned short*)alloc((size_t)HID * SEQ * 2);        // 4.2 MB
  float*          energ  = (float*)         alloc((size_t)SEQ * SEQ * 4);        // 16.8 MB
  unsigned short* attn   = (unsigned short*)alloc((size_t)SEQ * SEQ * 2);        // 8.4 MB
  unsigned short* out_bf = (unsigned short*)alloc((size_t)SEQ * 2 * HID * 2);    // 8.4 MB
  float*          y      = (float*)d_out;                                        // [SEQ][NOUT]

  // 1) embeddings -> bf16 x
  k_embed<<<SEQ, 128, 0, stream>>>(loc, tim, emb_loc, emb_tim, xbf);

  // 2) xg = x @ W_ih^T + (b_ih + b_hh)   [2048, 4096]
  k_gemm<1, 0, 0><<<dim3(SEQ / 128, G4H / 128), 256, 0, stream>>>(
      xbf, INP, W_ih, INP, xg, G4H, 0, SEQ, G4H, INP, b_ih, b_hh);

  // 3) LSTM scan (persistent, tag-sync)
  k_lstm<<<256, 256, 0, stream>>>(W_hh, xg, hglob, hs_bf, hsT_bf, out_bf);

  // 4) energies = hs @ hs^T (lower triangle only)
  k_gemm<0, 0, 1><<<dim3(SEQ / 128, SEQ / 128), 256, 0, stream>>>(
      hs_bf, HID, hs_bf, HID, energ, SEQ, 0, SEQ, SEQ, HID, nullptr, nullptr);

  // 5) causal softmax -> bf16 attn (zeros above diagonal)
  k_softmax<<<SEQ, 256, 0, stream>>>(energ, attn);

  // 6) context = attn @ hs -> right half of out_bf (bf16)
  k_gemm<0, 1, 0><<<dim3(SEQ / 128, HID / 128), 256, 0, stream>>>(
      attn, SEQ, hsT_bf, SEQ, out_bf, 2 * HID, HID, SEQ, HID, SEQ, nullptr, nullptr);

  // 7) y = out @ W_fc^T + b_fc  (fp32 W_fc converted to bf16 during staging)
  k_gemm<1, 0, 0><<<dim3(SEQ / 128, (NOUT + 127) / 128), 256, 0, stream>>>(
      out_bf, 2 * HID, W_fc, 2 * HID, y, NOUT, 0, SEQ, NOUT, 2 * HID, b_fc, nullptr);

  // 8) in-place log-softmax on d_out
  k_logsoftmax<<<SEQ, 256, 0, stream>>>(y);
}

// Round 2
// 6273.687 us; speedup vs baseline: 1.1378x; 1.1378x over previous
//
#include <hip/hip_runtime.h>
#include <hip/hip_bf16.h>

// Problem constants
#define SEQ   2048
#define HID   1024
#define INP   576
#define G4H   4096   // 4*HID
#define NOUT  32001

typedef __attribute__((ext_vector_type(8))) short bf16x8;
typedef __attribute__((ext_vector_type(4))) float f32x4;

__device__ __forceinline__ unsigned short f2bf(float f) {
  unsigned int u = __builtin_bit_cast(unsigned int, f);
  unsigned int r = (u + 0x7FFFu + ((u >> 16) & 1u)) >> 16;
  return (unsigned short)r;
}
__device__ __forceinline__ float bf2f(unsigned short h) {
  unsigned int u = ((unsigned int)h) << 16;
  return __builtin_bit_cast(float, u);
}
__device__ __forceinline__ float sigm_fast(float x) {
  return __builtin_amdgcn_rcpf(1.f + __expf(-x));
}
__device__ __forceinline__ float tanh_fast(float x) {
  // 1 - 2/(e^{2x}+1); saturates correctly at +-inf
  return 1.f - 2.f * __builtin_amdgcn_rcpf(1.f + __expf(2.f * x));
}

// ---------------------------------------------------------------- embedding
__global__ __launch_bounds__(128)
void k_embed(const int* __restrict__ loc, const int* __restrict__ tim,
             const float* __restrict__ el, const float* __restrict__ et,
             unsigned short* __restrict__ xbf) {
  int s = blockIdx.x;
  int l = loc[s], t = tim[s];
  for (int c = threadIdx.x; c < INP; c += 128) {
    float v = (c < 512) ? el[(size_t)l * 512 + c] : et[(size_t)t * 64 + (c - 512)];
    xbf[(size_t)s * INP + c] = f2bf(v);
  }
}

// ---------------------------------------------------------------- GEMM (B^T layout)
// C[m][n] = sum_k A[m][k] * Bt[n][k] (+ bias0[n] + bias1[n])
// A: bf16 [M][lda]. Bt: bf16 (BSRC=0) or fp32 (BSRC=1, converted during staging) [N][ldb].
// OUTBF: 0 -> fp32 C, 1 -> bf16 C. TRI: skip blocks fully above diagonal (energies).
template<int BSRC, int OUTBF, int TRI>
__global__ __launch_bounds__(256)
void k_gemm(const unsigned short* __restrict__ A, int lda,
            const void* __restrict__ B, int ldb,
            void* __restrict__ C, long long ldc, long long cofs,
            int M, int N, int K,
            const float* __restrict__ bias0, const float* __restrict__ bias1) {
  int m0 = blockIdx.x * 128;
  int n0 = blockIdx.y * 128;
  if (TRI && n0 > m0 + 127) return;

  __shared__ unsigned short sA[128][40];  // 32 + 8 pad
  __shared__ unsigned short sB[128][40];

  int tid = threadIdx.x;
  int lane = tid & 63;
  int wid = tid >> 6;
  int wm = (wid >> 1) * 64, wn = (wid & 1) * 64;
  int r16 = lane & 15, quad = lane >> 4;

  f32x4 acc[4][4];
#pragma unroll
  for (int i = 0; i < 4; ++i)
#pragma unroll
    for (int j = 0; j < 4; ++j)
#pragma unroll
      for (int r = 0; r < 4; ++r) acc[i][j][r] = 0.f;

  int nk = K / 32;
  for (int kt = 0; kt < nk; ++kt) {
    int k0 = kt * 32;
#pragma unroll
    for (int h = 0; h < 2; ++h) {       // A staging: 512 chunks of 8 bf16
      int c = tid + h * 256;
      int row = c >> 2, part = c & 3;
      bf16x8 av = *(const bf16x8*)(A + (size_t)(m0 + row) * lda + k0 + part * 8);
      *(bf16x8*)&sA[row][part * 8] = av;
    }
#pragma unroll
    for (int h = 0; h < 2; ++h) {       // B staging (optionally fp32->bf16)
      int c = tid + h * 256;
      int row = c >> 2, part = c & 3;
      int gr = n0 + row;
      bf16x8 bv;
      if (gr < N) {
        if (BSRC == 0) {
          bv = *(const bf16x8*)((const unsigned short*)B + (size_t)gr * ldb + k0 + part * 8);
        } else {
          const float* bp = (const float*)B + (size_t)gr * ldb + k0 + part * 8;
          f32x4 b0 = *(const f32x4*)bp;
          f32x4 b1 = *(const f32x4*)(bp + 4);
#pragma unroll
          for (int z = 0; z < 4; ++z) bv[z] = (short)f2bf(b0[z]);
#pragma unroll
          for (int z = 0; z < 4; ++z) bv[4 + z] = (short)f2bf(b1[z]);
        }
      } else {
#pragma unroll
        for (int z = 0; z < 8; ++z) bv[z] = 0;
      }
      *(bf16x8*)&sB[row][part * 8] = bv;
    }
    __syncthreads();
    bf16x8 af[4], bfr[4];
#pragma unroll
    for (int i = 0; i < 4; ++i) {
      af[i]  = *(const bf16x8*)&sA[wm + i * 16 + r16][quad * 8];
      bfr[i] = *(const bf16x8*)&sB[wn + i * 16 + r16][quad * 8];
    }
#pragma unroll
    for (int i = 0; i < 4; ++i)
#pragma unroll
      for (int j = 0; j < 4; ++j)
        acc[i][j] = __builtin_amdgcn_mfma_f32_16x16x32_bf16(af[i], bfr[j], acc[i][j], 0, 0, 0);
    __syncthreads();
  }

  // epilogue: row = quad*4 + r, col = lane&15 within each 16x16 tile
#pragma unroll
  for (int i = 0; i < 4; ++i) {
    int rowb = m0 + wm + i * 16 + quad * 4;
#pragma unroll
    for (int j = 0; j < 4; ++j) {
      int col = n0 + wn + j * 16 + r16;
      if (col >= N) continue;
      float b = 0.f;
      if (bias0) b += bias0[col];
      if (bias1) b += bias1[col];
#pragma unroll
      for (int r = 0; r < 4; ++r) {
        float v = acc[i][j][r] + b;
        size_t idx = (size_t)(rowb + r) * (size_t)ldc + (size_t)cofs + col;
        if (OUTBF) ((unsigned short*)C)[idx] = f2bf(v);
        else       ((float*)C)[idx] = v;
      }
    }
  }
}

// ---------------------------------------------------------------- persistent LSTM scan
// 256 blocks (1/CU, co-resident). Block b owns h[4b..4b+4) i.e. 16 gate rows.
// Thread map: r = tid&15 (local gate row), kl = tid>>4 (k-slice of 64).
// W_hh rows live in REGISTERS (64 fp32/thread). h published as (tag<<16)|bf16
// via agent-scope relaxed atomics; consumers poll all 4 of their words per
// round in parallel (single round = one coherence-point latency).
__global__ __launch_bounds__(256)
void k_lstm(const float* __restrict__ Whh, const float* __restrict__ xg,
            unsigned int* __restrict__ hglob,
            unsigned short* __restrict__ hs_bf, unsigned short* __restrict__ hsT_bf,
            unsigned short* __restrict__ out_bf) {
  __shared__ float sH[1024];
  __shared__ float sP[4][16];

  int blk = blockIdx.x;
  int tid = threadIdx.x;
  int r = tid & 15, kl = tid >> 4;
  // local row r -> gate q=r>>2, lane j=r&3 -> global gate row q*HID + blk*4 + j
  int gr_row = (r >> 2) * HID + blk * 4 + (r & 3);

  // W chunk in registers: W_hh[gr_row][kl*64 .. kl*64+64]
  float wreg[64];
  {
    const float* wrow = Whh + (size_t)gr_row * HID + kl * 64;
#pragma unroll
    for (int c = 0; c < 16; ++c) {
      f32x4 w = *(const f32x4*)(wrow + c * 4);
      wreg[c * 4 + 0] = w[0]; wreg[c * 4 + 1] = w[1];
      wreg[c * 4 + 2] = w[2]; wreg[c * 4 + 3] = w[3];
    }
  }
  float cst = 0.f;  // cell state (lives in lanes tid<4)

  for (int t = 0; t < SEQ; ++t) {
    float xgv = 0.f;
    if (tid < 16) xgv = xg[(size_t)t * G4H + (tid >> 2) * HID + blk * 4 + (tid & 3)];

    if (t == 0) {
      f32x4 z4 = {0.f, 0.f, 0.f, 0.f};
      *(f32x4*)&sH[tid * 4] = z4;
    } else {
      const unsigned int* src = hglob + (size_t)(t - 1) * HID + tid * 4;
      unsigned int want = (unsigned int)t;
      unsigned int v0, v1, v2, v3;
      for (;;) {  // all 4 loads in flight per round
        v0 = __hip_atomic_load(src + 0, __ATOMIC_RELAXED, __HIP_MEMORY_SCOPE_AGENT);
        v1 = __hip_atomic_load(src + 1, __ATOMIC_RELAXED, __HIP_MEMORY_SCOPE_AGENT);
        v2 = __hip_atomic_load(src + 2, __ATOMIC_RELAXED, __HIP_MEMORY_SCOPE_AGENT);
        v3 = __hip_atomic_load(src + 3, __ATOMIC_RELAXED, __HIP_MEMORY_SCOPE_AGENT);
        if (((v0 >> 16) == want) & ((v1 >> 16) == want) &
            ((v2 >> 16) == want) & ((v3 >> 16) == want)) break;
      }
      f32x4 hv;
      hv[0] = bf2f((unsigned short)(v0 & 0xFFFFu));
      hv[1] = bf2f((unsigned short)(v1 & 0xFFFFu));
      hv[2] = bf2f((unsigned short)(v2 & 0xFFFFu));
      hv[3] = bf2f((unsigned short)(v3 & 0xFFFFu));
      *(f32x4*)&sH[tid * 4] = hv;
    }
    __syncthreads();

    // dot: thread (r,kl) covers k in [kl*64, kl*64+64). sH reads are
    // wave-uniform per 16-lane phase group (broadcast, conflict-free).
    float acc = 0.f;
#pragma unroll
    for (int c = 0; c < 16; ++c) {
      f32x4 hv = *(const f32x4*)&sH[kl * 64 + c * 4];
      acc += wreg[c * 4 + 0] * hv[0] + wreg[c * 4 + 1] * hv[1] +
             wreg[c * 4 + 2] * hv[2] + wreg[c * 4 + 3] * hv[3];
    }
    // reduce over kl within wave (kl spans lane bits 4..5)
    acc += __shfl_xor(acc, 16, 64);
    acc += __shfl_xor(acc, 32, 64);
    int lane = tid & 63, w = tid >> 6;
    if (lane < 16) sP[w][lane] = acc;
    __syncthreads();

    if (tid < 16) {
      float z = sP[0][tid] + sP[1][tid] + sP[2][tid] + sP[3][tid] + xgv;
      int q = tid >> 2;
      float a = (q == 2) ? tanh_fast(z) : sigm_fast(z);
      int j = tid & 3;
      float gi = __shfl(a, j, 64);
      float gf = __shfl(a, 4 + j, 64);
      float gg = __shfl(a, 8 + j, 64);
      float go = __shfl(a, 12 + j, 64);
      if (tid < 4) {
        cst = gf * cst + gi * gg;
        float h = go * tanh_fast(cst);
        unsigned short hb = f2bf(h);
        int gj = blk * 4 + j;
        __hip_atomic_store(&hglob[(size_t)t * HID + gj],
                           (((unsigned int)(t + 1)) << 16) | (unsigned int)hb,
                           __ATOMIC_RELAXED, __HIP_MEMORY_SCOPE_AGENT);
        hs_bf[(size_t)t * HID + gj] = hb;          // A/B for energies
        hsT_bf[(size_t)gj * SEQ + t] = hb;         // B^T for context GEMM
        out_bf[(size_t)t * (2 * HID) + gj] = hb;   // left half of concat(hs, context)
      }
    }
    // next iteration's stage-2 barrier orders sP reads vs. rewrites
  }
}

// ---------------------------------------------------------------- causal softmax rows
__global__ __launch_bounds__(256)
void k_softmax(const float* __restrict__ E, unsigned short* __restrict__ P) {
  int i = blockIdx.x;
  int n = i + 1;
  const float* e = E + (size_t)i * SEQ;
  __shared__ float red[4];
  int tid = threadIdx.x, lane = tid & 63, w = tid >> 6;

  float m = -1e30f;
  for (int j = tid; j < n; j += 256) m = fmaxf(m, e[j]);
  for (int o = 32; o; o >>= 1) m = fmaxf(m, __shfl_xor(m, o));
  if (lane == 0) red[w] = m;
  __syncthreads();
  m = fmaxf(fmaxf(red[0], red[1]), fmaxf(red[2], red[3]));
  __syncthreads();

  float s = 0.f;
  for (int j = tid; j < n; j += 256) s += __expf(e[j] - m);
  for (int o = 32; o; o >>= 1) s += __shfl_xor(s, o);
  if (lane == 0) red[w] = s;
  __syncthreads();
  s = red[0] + red[1] + red[2] + red[3];
  float inv = 1.f / s;

  unsigned short* p = P + (size_t)i * SEQ;
  for (int j = tid; j < SEQ; j += 256)
    p[j] = (j < n) ? f2bf(__expf(e[j] - m) * inv) : (unsigned short)0;
}

// ---------------------------------------------------------------- in-place log-softmax
// online max+sum in one read pass, then one read+write pass
__global__ __launch_bounds__(256)
void k_logsoftmax(float* __restrict__ Y) {
  int i = blockIdx.x;
  float* y = Y + (size_t)i * (size_t)NOUT;
  __shared__ float redm[4], reds[4];
  int tid = threadIdx.x, lane = tid & 63, w = tid >> 6;

  float m = -1e30f, s = 0.f;
  for (int j = tid; j < NOUT; j += 256) {
    float v = y[j];
    float nm = fmaxf(m, v);
    s = s * __expf(m - nm) + __expf(v - nm);
    m = nm;
  }
  for (int o = 32; o; o >>= 1) {
    float om = __shfl_xor(m, o), os = __shfl_xor(s, o);
    float nm = fmaxf(m, om);
    s = s * __expf(m - nm) + os * __expf(om - nm);
    m = nm;
  }
  if (lane == 0) { redm[w] = m; reds[w] = s; }
  __syncthreads();
  if (tid == 0) {
    float fm = redm[0], fs = reds[0];
    for (int k = 1; k < 4; ++k) {
      float nm = fmaxf(fm, redm[k]);
      fs = fs * __expf(fm - nm) + reds[k] * __expf(redm[k] - nm);
      fm = nm;
    }
    redm[0] = fm + logf(fs);
  }
  __syncthreads();
  float lse = redm[0];
  for (int j = tid; j < NOUT; j += 256) y[j] -= lse;
}

// ---------------------------------------------------------------- launch
extern "C" void kernel_launch(void* const* d_in, const int* in_sizes, int n_in,
                              void* d_out, int out_size, void* d_ws, size_t ws_size,
                              hipStream_t stream) {
  (void)in_sizes; (void)n_in; (void)out_size; (void)ws_size;
  const int*   loc     = (const int*)d_in[0];
  const int*   tim     = (const int*)d_in[1];
  const float* emb_loc = (const float*)d_in[2];
  const float* emb_tim = (const float*)d_in[3];
  const float* W_ih    = (const float*)d_in[4];
  const float* W_hh    = (const float*)d_in[5];
  const float* b_ih    = (const float*)d_in[6];
  const float* b_hh    = (const float*)d_in[7];
  const float* W_fc    = (const float*)d_in[8];
  const float* b_fc    = (const float*)d_in[9];

  char* ws = (char*)d_ws;
  size_t off = 0;
  auto alloc = [&](size_t bytes) {
    void* p = ws + off;
    off += (bytes + 255) & ~(size_t)255;
    return p;
  };
  unsigned short* xbf    = (unsigned short*)alloc((size_t)SEQ * INP * 2);        // 2.4 MB
  float*          xg     = (float*)         alloc((size_t)SEQ * G4H * 4);        // 33.6 MB
  unsigned int*   hglob  = (unsigned int*)  alloc((size_t)SEQ * HID * 4);        // 8.4 MB
  unsigned short* hs_bf  = (unsigned short*)alloc((size_t)SEQ * HID * 2);        // 4.2 MB
  unsigned short* hsT_bf = (unsigned short*)alloc((size_t)HID * SEQ * 2);        // 4.2 MB
  float*          energ  = (float*)         alloc((size_t)SEQ * SEQ * 4);        // 16.8 MB
  unsigned short* attn   = (unsigned short*)alloc((size_t)SEQ * SEQ * 2);        // 8.4 MB
  unsigned short* out_bf = (unsigned short*)alloc((size_t)SEQ * 2 * HID * 2);    // 8.4 MB
  float*          y      = (float*)d_out;                                        // [SEQ][NOUT]

  // 1) embeddings -> bf16 x
  k_embed<<<SEQ, 128, 0, stream>>>(loc, tim, emb_loc, emb_tim, xbf);

  // 2) xg = x @ W_ih^T + (b_ih + b_hh)   [2048, 4096]
  k_gemm<1, 0, 0><<<dim3(SEQ / 128, G4H / 128), 256, 0, stream>>>(
      xbf, INP, W_ih, INP, xg, G4H, 0, SEQ, G4H, INP, b_ih, b_hh);

  // 3) LSTM scan (persistent, tag-sync, W in registers)
  k_lstm<<<256, 256, 0, stream>>>(W_hh, xg, hglob, hs_bf, hsT_bf, out_bf);

  // 4) energies = hs @ hs^T (lower triangle only)
  k_gemm<0, 0, 1><<<dim3(SEQ / 128, SEQ / 128), 256, 0, stream>>>(
      hs_bf, HID, hs_bf, HID, energ, SEQ, 0, SEQ, SEQ, HID, nullptr, nullptr);

  // 5) causal softmax -> bf16 attn (zeros above diagonal)
  k_softmax<<<SEQ, 256, 0, stream>>>(energ, attn);

  // 6) context = attn @ hs -> right half of out_bf (bf16)
  k_gemm<0, 1, 0><<<dim3(SEQ / 128, HID / 128), 256, 0, stream>>>(
      attn, SEQ, hsT_bf, SEQ, out_bf, 2 * HID, HID, SEQ, HID, SEQ, nullptr, nullptr);

  // 7) y = out @ W_fc^T + b_fc  (fp32 W_fc converted to bf16 during staging)
  k_gemm<1, 0, 0><<<dim3(SEQ / 128, (NOUT + 127) / 128), 256, 0, stream>>>(
      out_bf, 2 * HID, W_fc, 2 * HID, y, NOUT, 0, SEQ, NOUT, 2 * HID, b_fc, nullptr);

  // 8) in-place log-softmax on d_out
  k_logsoftmax<<<SEQ, 256, 0, stream>>>(y);
}